// Round 5
// baseline (314.621 us; speedup 1.0000x reference)
//
#include <hip/hip_runtime.h>
#include <hip/hip_bf16.h>
#include <math.h>

#define BB 8
#define TT 2048
#define CC 1024
#define HH 64
#define NROW (BB*TT)          // 16384
#define NST (NROW*HH)         // 1048576 elements per output component
#define KK2 2048              // combined GEMM K = 2C
#define NN 384                // Bt rows (6 components)
#define GN 256                // G cols: [kr|ki|qr|qi]  (512 B rows, exact lines)
#define VTP 2080              // VT row stride in elements (4160 B, breaks 4KB aliasing)

typedef __attribute__((ext_vector_type(8))) short short8;
typedef __attribute__((ext_vector_type(4))) float f32x4;

static __device__ inline unsigned pk_bf16(float a, float b) {
    __hip_bfloat162 h = __float22bfloat162_rn(make_float2(a, b));
    unsigned u; __builtin_memcpy(&u, &h, 4); return u;
}
static __device__ inline short f2bf_s(float a) {
    __hip_bfloat16 h = __float2bfloat16(a);
    short s; __builtin_memcpy(&s, &h, 2); return s;
}
static __device__ inline short8 neg8(short8 a) {
    short8 r;
    #pragma unroll
    for (int i = 0; i < 8; ++i) r[i] = a[i] ^ (short)0x8000;
    return r;
}

// async global->LDS, 16B per lane; LDS dest is WAVE-UNIFORM base (HW adds lane*16)
static __device__ inline void async16(const void* g, void* l) {
    __builtin_amdgcn_global_load_lds(
        (const __attribute__((address_space(1))) void*)g,
        (__attribute__((address_space(3))) void*)l,
        16, 0, 0);
}

// ---------------------------------------------------------------------------
// Kernel 0: build Bt[n][k] bf16. n = 64*g + h, g in [kr,ki,qr,qi,vr,vi];
// real: [Wr;-Wi], imag: [Wi;Wr].
// ---------------------------------------------------------------------------
__global__ __launch_bounds__(256) void prep_kernel(
    const float* __restrict__ Wkr, const float* __restrict__ Wki,
    const float* __restrict__ Wqr, const float* __restrict__ Wqi,
    const float* __restrict__ Wvr, const float* __restrict__ Wvi,
    short* __restrict__ Bt)
{
    const int n = blockIdx.x;
    const int g = n >> 6, h = n & 63;
    const int p = g >> 1;
    const bool im = g & 1;
    const float* Wr = (p == 0) ? Wkr : (p == 1) ? Wqr : Wvr;
    const float* Wi = (p == 0) ? Wki : (p == 1) ? Wqi : Wvi;
    const float* W1 = im ? Wi : Wr;
    const float* W2 = im ? Wr : Wi;
    const float s2 = im ? 1.f : -1.f;

    #pragma unroll
    for (int j = 0; j < 8; ++j) {
        int k = threadIdx.x + 256 * j;
        float v = (k < CC) ? W1[k * HH + h] : s2 * W2[(k - CC) * HH + h];
        Bt[(size_t)n * KK2 + k] = f2bf_s(v);
    }
}

// ---------------------------------------------------------------------------
// Kernel 1: bf16 MFMA GEMM, fused fp32->bf16, software-pipelined (T3/T4).
// BM=128 BN=64 BK=64, grid (128,6). Double-buffered LDS, ONE raw s_barrier
// per K-step with COUNTED vmcnt (never 0 in the loop) so prefetch loads stay
// in flight across barriers:
//   iter i: asyncB(i+1)->sB[q] | cvt+swz-ds_write A(i+1)->sA[q] (reg-dep wait
//   retires A(i+1) only) | issue 8 fp32 A-loads(i+2) | ds_read+16 MFMA on p |
//   s_waitcnt vmcnt(8) lgkmcnt(0) (retires the 2 asyncB; A(i+2) in flight) |
//   s_barrier | sched_barrier(0)   [rule 18]
// All 6 comp-blocks of a row-panel land on one XCD (128%8==0) -> A read ~once.
// ---------------------------------------------------------------------------
#define LDP 72    // epilogue G staging stride (elements)
#define STP 136   // epilogue sT row stride (elements), 16B-aligned
#define LDSA (128*64)
#define LDSB (64*64)

__global__ __launch_bounds__(256) void proj_gemm(
    const float* __restrict__ xr, const float* __restrict__ xi,
    const short* __restrict__ Bt,
    short* __restrict__ G, short* __restrict__ VT)
{
    __shared__ __attribute__((aligned(16))) short sAB[2*LDSA + 2*LDSB]; // 48 KB

    const int tid = threadIdx.x;
    const int mbase = blockIdx.x * 128;
    const int comp = blockIdx.y;                 // 0..5

    const int wave = tid >> 6, lane = tid & 63;
    const int wr = wave >> 1, wc = wave & 1;     // 64-row half, 32-col half
    const int quad = lane >> 4, lm = lane & 15;

    const int lgrp = lane >> 3;                  // B staging: row within 8-row group
    const int lslot = lane & 7;
    const int scol = ((lslot ^ lgrp) << 4);      // swizzled byte col within row

    // A staging decomposition: 2 threads per row, 32 fp32 (=128B) each
    const int rr = tid >> 1, hf = tid & 1;

    const char* Bg = (const char*)(Bt + (size_t)comp * 64 * KK2);

    f32x4 acc[4][2] = {};
    float4 av[8];

    // ---- pipeline stage helpers ----
    #define LOAD_A(ks)  do {                                                    \
        const float* __restrict__ srcA_ = ((ks) < 16) ? xr : xi;                \
        const int kc_ = ((ks) & 15) * 64;                                       \
        const float4* ap_ = (const float4*)                                     \
            &srcA_[(size_t)(mbase + rr) * CC + kc_ + hf * 32];                  \
        _Pragma("unroll")                                                       \
        for (int j_ = 0; j_ < 8; ++j_) av[j_] = ap_[j_];                        \
    } while (0)

    #define STAGE_B(ks, pb)  do {                                               \
        char* sBp_ = (char*)(sAB + 2*LDSA + (pb)*LDSB);                         \
        _Pragma("unroll")                                                       \
        for (int i_ = 0; i_ < 2; ++i_) {                                        \
            int q_ = wave * 2 + i_;                                             \
            async16(Bg + (size_t)(q_*8 + lgrp) * (KK2*2) + (ks)*128 + scol,     \
                    sBp_ + q_ * 1024);                                          \
        }                                                                       \
    } while (0)

    #define WRITE_A(pa)  do {                                                   \
        short* sAp_ = sAB + (pa)*LDSA;                                          \
        _Pragma("unroll")                                                       \
        for (int lg_ = 0; lg_ < 4; ++lg_) {                                     \
            uint4 w_;                                                           \
            w_.x = pk_bf16(av[2*lg_].x,   av[2*lg_].y);                         \
            w_.y = pk_bf16(av[2*lg_].z,   av[2*lg_].w);                         \
            w_.z = pk_bf16(av[2*lg_+1].x, av[2*lg_+1].y);                       \
            w_.w = pk_bf16(av[2*lg_+1].z, av[2*lg_+1].w);                       \
            int g_ = hf * 4 + lg_;                                              \
            int ce_ = ((g_ ^ (rr & 7)) << 3);                                   \
            *(uint4*)&sAp_[rr * 64 + ce_] = w_;                                 \
        }                                                                       \
    } while (0)

    #define COMPUTE(pc)  do {                                                   \
        short* sAp_ = sAB + (pc)*LDSA;                                          \
        short* sBp_ = sAB + 2*LDSA + (pc)*LDSB;                                 \
        _Pragma("unroll")                                                       \
        for (int kk_ = 0; kk_ < 2; ++kk_) {                                     \
            const int cs_ = (kk_*32 + quad*8) ^ ((lm & 7) << 3);                \
            short8 af_[4], bf_[2];                                              \
            _Pragma("unroll")                                                   \
            for (int mi_ = 0; mi_ < 4; ++mi_)                                   \
                af_[mi_] = *(const short8*)&sAp_[(64*wr + 16*mi_ + lm)*64 + cs_];\
            _Pragma("unroll")                                                   \
            for (int ni_ = 0; ni_ < 2; ++ni_)                                   \
                bf_[ni_] = *(const short8*)&sBp_[(32*wc + 16*ni_ + lm)*64 + cs_];\
            _Pragma("unroll")                                                   \
            for (int mi_ = 0; mi_ < 4; ++mi_)                                   \
                _Pragma("unroll")                                               \
                for (int ni_ = 0; ni_ < 2; ++ni_)                               \
                    acc[mi_][ni_] = __builtin_amdgcn_mfma_f32_16x16x32_bf16(    \
                        af_[mi_], bf_[ni_], acc[mi_][ni_], 0, 0, 0);            \
        }                                                                       \
    } while (0)

    // ---- prologue: stage tile 0, prefetch A(1) ----
    LOAD_A(0);
    STAGE_B(0, 0);
    WRITE_A(0);                 // compiler reg-dep wait retires A(0) loads
    LOAD_A(1);
    // outstanding: asyncB(0) x2 (oldest) + A(1) x8 -> retire asyncB(0)
    asm volatile("s_waitcnt vmcnt(8) lgkmcnt(0)" ::: "memory");
    __builtin_amdgcn_s_barrier();
    __builtin_amdgcn_sched_barrier(0);

    // ---- main loop: compute tile i, stage tile i+1, prefetch A(i+2) ----
    for (int i = 0; i < 31; ++i) {
        const int p = i & 1, q = p ^ 1;
        STAGE_B(i + 1, q);
        WRITE_A(q);             // reg-dep wait retires A(i+1) only (vmcnt(2))
        const int nks = (i + 2 < 32) ? i + 2 : 31;   // clamped dummy on last
        LOAD_A(nks);
        COMPUTE(p);
        // outstanding: asyncB(i+1) x2 (oldest) + A(i+2) x8 -> retire asyncB
        asm volatile("s_waitcnt vmcnt(8) lgkmcnt(0)" ::: "memory");
        __builtin_amdgcn_s_barrier();
        __builtin_amdgcn_sched_barrier(0);
    }
    COMPUTE(1);                 // tile 31 (p = 31&1 = 1)

    __syncthreads();            // epilogue: safe to reuse sAB (drains all)

    if (comp < 4) {
        short* sG = sAB;   // [128][LDP]
        #pragma unroll
        for (int mi = 0; mi < 4; ++mi)
            #pragma unroll
            for (int ni = 0; ni < 2; ++ni)
                #pragma unroll
                for (int r = 0; r < 4; ++r)
                    sG[(64*wr + 16*mi + quad*4 + r) * LDP + 32*wc + 16*ni + lm] =
                        f2bf_s(acc[mi][ni][r]);
        __syncthreads();
        #pragma unroll
        for (int j = 0; j < 4; ++j) {
            int id = tid + 256 * j;
            int row = id >> 3, c8 = id & 7;       // 8 x 16B per row
            uint4 v = *(const uint4*)&sG[row * LDP + c8 * 8];
            *(uint4*)&G[(size_t)(mbase + row) * GN + comp*64 + c8*8] = v;
        }
    } else {
        short* sT = sAB;   // [64][STP]
        const int vcomp = comp - 4;
        const int b = mbase >> 11;
        const int tb = mbase & 2047;
        #pragma unroll
        for (int mi = 0; mi < 4; ++mi)
            #pragma unroll
            for (int ni = 0; ni < 2; ++ni)
                #pragma unroll
                for (int r = 0; r < 4; ++r)
                    sT[(32*wc + 16*ni + lm) * STP + 64*wr + 16*mi + quad*4 + r] =
                        f2bf_s(acc[mi][ni][r]);
        __syncthreads();
        #pragma unroll
        for (int j = 0; j < 4; ++j) {
            int id = tid + 256 * j;
            int h = id >> 4, c = id & 15;         // 16 x 16B per h-row
            uint4 v = *(const uint4*)&sT[h * STP + c * 8];
            *(uint4*)&VT[(((size_t)vcomp*BB + b)*64 + h)*VTP + tb + c*8] = v;
        }
    }
    #undef LOAD_A
    #undef STAGE_B
    #undef WRITE_A
    #undef COMPUTE
}

// ---------------------------------------------------------------------------
// Kernel 2: MFMA flash attention, log2-domain online softmax.
// Grid is (b, j): linear bid % 8 == b -> all blocks of batch b on XCD b,
// K/V panels stay L2-resident (FETCH 6.2 MB measured, was 34.6).
// ---------------------------------------------------------------------------
#define PLDS 72
#define SC2 0.18033688f      // 0.125 * log2(e): softmax in exp2 domain

__global__ __launch_bounds__(256) void attn_kernel(
    const short* __restrict__ G,
    const short* __restrict__ VT,
    float* __restrict__ out)
{
    __shared__ float comb[4][16][128];
    __shared__ float cmw[4][16], clw[4][16];

    const int tid = threadIdx.x;
    const int wave = tid >> 6, lane = tid & 63;
    const int quad = lane >> 4, lm = lane & 15;
    const int b = blockIdx.x;                               // XCD affinity: bid%8 == b
    const int j = (int)(gridDim.y - 1) - (int)blockIdx.y;   // longest first
    const int qbase = j * 16;
    const int nkt = (j >> 2) + 1;    // k-tiles of 64 tokens

    const short* Qrow = G + ((size_t)(b*TT + qbase + lm)) * GN + 128;
    short8 A1[4], A2[4];
    #pragma unroll
    for (int ks = 0; ks < 4; ++ks)
        A1[ks] = *(const short8*)(Qrow + ks*32 + quad*8);
    A2[0] = A1[2]; A2[1] = A1[3];
    A2[2] = neg8(A1[0]); A2[3] = neg8(A1[1]);

    short8 ones;
    #pragma unroll
    for (int i = 0; i < 8; ++i) ones[i] = (short)0x3F80;   // bf16 1.0

    f32x4 Or[4], Oi[4];
    #pragma unroll
    for (int h = 0; h < 4; ++h)
        #pragma unroll
        for (int r = 0; r < 4; ++r) { Or[h][r] = 0.f; Oi[h][r] = 0.f; }
    f32x4 Ol = {0.f, 0.f, 0.f, 0.f};            // row-sums via ones-MFMA
    float m[4];
    #pragma unroll
    for (int r = 0; r < 4; ++r) m[r] = -INFINITY;

    short* Pw = (short*)&comb[wave][0][0];
    const short* Vrb = VT + (size_t)b * 64 * VTP;
    const short* Vib = VT + ((size_t)BB + b) * 64 * VTP;

    for (int kt = wave; kt < nkt; kt += 4) {
        const int kb = kt * 64;
        const short* Kt = G + ((size_t)(b*TT + kb)) * GN;

        // ---- hoist ALL K loads: one latency exposure instead of 4 ----
        short8 Kf[4][4];
        #pragma unroll
        for (int nt = 0; nt < 4; ++nt) {
            const short* Krow = Kt + (size_t)(nt*16 + lm) * GN;
            #pragma unroll
            for (int ks = 0; ks < 4; ++ks)
                Kf[nt][ks] = *(const short8*)(Krow + ks*32 + quad*8);
        }

        f32x4 mag[4];
        #pragma unroll
        for (int nt = 0; nt < 4; ++nt) {
            f32x4 sr = {0.f,0.f,0.f,0.f}, si = {0.f,0.f,0.f,0.f};
            __builtin_amdgcn_s_setprio(1);
            #pragma unroll
            for (int ks = 0; ks < 4; ++ks) {
                sr = __builtin_amdgcn_mfma_f32_16x16x32_bf16(A1[ks], Kf[nt][ks], sr, 0,0,0);
                si = __builtin_amdgcn_mfma_f32_16x16x32_bf16(A2[ks], Kf[nt][ks], si, 0,0,0);
            }
            __builtin_amdgcn_s_setprio(0);
            int tok = kb + nt*16 + lm;
            #pragma unroll
            for (int r = 0; r < 4; ++r) {
                float v = __builtin_amdgcn_sqrtf(
                              fmaf(sr[r], sr[r], fmaf(si[r], si[r], 1e-4f))) * SC2;
                int qrow = qbase + quad*4 + r;
                mag[nt][r] = (tok > qrow) ? -INFINITY : v;
            }
        }

        // ---- issue V loads now; softmax below hides their latency ----
        short8 Vr[4][2], Vi[4][2];
        #pragma unroll
        for (int ht = 0; ht < 4; ++ht) {
            const short* vr0 = Vrb + (size_t)(ht*16 + lm) * VTP + kb + quad*8;
            const short* vi0 = Vib + (size_t)(ht*16 + lm) * VTP + kb + quad*8;
            Vr[ht][0] = *(const short8*)(vr0);
            Vr[ht][1] = *(const short8*)(vr0 + 32);
            Vi[ht][0] = *(const short8*)(vi0);
            Vi[ht][1] = *(const short8*)(vi0 + 32);
        }

        float tm[4];
        #pragma unroll
        for (int r = 0; r < 4; ++r)
            tm[r] = fmaxf(fmaxf(mag[0][r], mag[1][r]), fmaxf(mag[2][r], mag[3][r]));
        #pragma unroll
        for (int d = 1; d < 16; d <<= 1)
            #pragma unroll
            for (int r = 0; r < 4; ++r)
                tm[r] = fmaxf(tm[r], __shfl_xor(tm[r], d, 16));

        // defer-max: rescale only when the running max actually grows past slack
        int need = (tm[0] > m[0] + 8.f) | (tm[1] > m[1] + 8.f) |
                   (tm[2] > m[2] + 8.f) | (tm[3] > m[3] + 8.f);
        if (__any(need)) {
            float al[4];
            #pragma unroll
            for (int r = 0; r < 4; ++r) {
                float mn = fmaxf(m[r], tm[r]);
                al[r] = __builtin_amdgcn_exp2f(m[r] - mn);
                m[r] = mn;
            }
            #pragma unroll
            for (int h = 0; h < 4; ++h)
                #pragma unroll
                for (int r = 0; r < 4; ++r) { Or[h][r] *= al[r]; Oi[h][r] *= al[r]; }
            #pragma unroll
            for (int r = 0; r < 4; ++r) Ol[r] *= al[r];
        }

        #pragma unroll
        for (int nt = 0; nt < 4; ++nt)
            #pragma unroll
            for (int r = 0; r < 4; ++r) {
                float p = __builtin_amdgcn_exp2f(mag[nt][r] - m[r]);
                Pw[(quad*4 + r) * PLDS + nt*16 + lm] = f2bf_s(p);
            }
        short8 Af0 = *(const short8*)&Pw[lm * PLDS + quad*8];
        short8 Af1 = *(const short8*)&Pw[lm * PLDS + 32 + quad*8];

        __builtin_amdgcn_s_setprio(1);
        Ol = __builtin_amdgcn_mfma_f32_16x16x32_bf16(Af0, ones, Ol, 0,0,0);
        Ol = __builtin_amdgcn_mfma_f32_16x16x32_bf16(Af1, ones, Ol, 0,0,0);
        __builtin_amdgcn_s_setprio(0);

        #pragma unroll
        for (int ht = 0; ht < 4; ++ht) {
            __builtin_amdgcn_s_setprio(1);
            Or[ht] = __builtin_amdgcn_mfma_f32_16x16x32_bf16(Af0, Vr[ht][0], Or[ht], 0,0,0);
            Or[ht] = __builtin_amdgcn_mfma_f32_16x16x32_bf16(Af1, Vr[ht][1], Or[ht], 0,0,0);
            Oi[ht] = __builtin_amdgcn_mfma_f32_16x16x32_bf16(Af0, Vi[ht][0], Oi[ht], 0,0,0);
            Oi[ht] = __builtin_amdgcn_mfma_f32_16x16x32_bf16(Af1, Vi[ht][1], Oi[ht], 0,0,0);
            __builtin_amdgcn_s_setprio(0);
        }
    }

    __syncthreads();

    #pragma unroll
    for (int ht = 0; ht < 4; ++ht)
        #pragma unroll
        for (int r = 0; r < 4; ++r) {
            comb[wave][quad*4 + r][ht*16 + lm]      = Or[ht][r];
            comb[wave][quad*4 + r][64 + ht*16 + lm] = Oi[ht][r];
        }
    if (lm == 0) {
        #pragma unroll
        for (int r = 0; r < 4; ++r) {
            cmw[wave][quad*4 + r] = m[r];
            clw[wave][quad*4 + r] = Ol[r];
        }
    }
    __syncthreads();

    for (int e = tid; e < 16*128; e += 256) {
        int q = e >> 7, h = e & 127;
        float mstar = fmaxf(fmaxf(cmw[0][q], cmw[1][q]), fmaxf(cmw[2][q], cmw[3][q]));
        float osum = 0.f, lsum = 0.f;
        #pragma unroll
        for (int w = 0; w < 4; ++w) {
            float f = __builtin_amdgcn_exp2f(cmw[w][q] - mstar);
            osum = fmaf(f, comb[w][q][h], osum);
            lsum = fmaf(f, clw[w][q], lsum);
        }
        float res = osum / lsum;
        int comp = h >> 6, hh = h & 63;
        out[(size_t)comp * NST + ((size_t)(b*TT + qbase + q)) * HH + hh] = res;
    }
}

extern "C" void kernel_launch(void* const* d_in, const int* in_sizes, int n_in,
                              void* d_out, int out_size, void* d_ws, size_t ws_size,
                              hipStream_t stream)
{
    const float* xr  = (const float*)d_in[0];
    const float* xi  = (const float*)d_in[1];
    const float* Wkr = (const float*)d_in[2];
    const float* Wki = (const float*)d_in[3];
    const float* Wqr = (const float*)d_in[4];
    const float* Wqi = (const float*)d_in[5];
    const float* Wvr = (const float*)d_in[6];
    const float* Wvi = (const float*)d_in[7];

    short* Bt = (short*)d_ws;                               // 1.5 MB
    short* G  = (short*)((char*)d_ws + (2u  << 20));        // 8 MB  [16384][256]
    short* VT = (short*)((char*)d_ws + (11u << 20));        // 4.3 MB [2][8][64][VTP]
    float* out = (float*)d_out;

    prep_kernel<<<NN, 256, 0, stream>>>(Wkr, Wki, Wqr, Wqi, Wvr, Wvi, Bt);

    dim3 g1(NROW / 128, 6);
    proj_gemm<<<g1, 256, 0, stream>>>(xr, xi, Bt, G, VT);

    dim3 g3(BB, TT / 16);   // bid%8 == b -> per-batch XCD affinity
    attn_kernel<<<g3, 256, 0, stream>>>(G, VT, out);
}

// Round 6
// 246.258 us; speedup vs baseline: 1.2776x; 1.2776x over previous
//
#include <hip/hip_runtime.h>
#include <hip/hip_bf16.h>
#include <math.h>

#define BB 8
#define TT 2048
#define CC 1024
#define HH 64
#define NROW (BB*TT)          // 16384
#define NST (NROW*HH)         // 1048576 elements per output component
#define KK2 2048              // combined GEMM K = 2C
#define NN 384                // Bt rows (6 components)
#define GN 256                // G cols: [kr|ki|qr|qi]  (512 B rows, exact lines)
#define VTP 2080              // VT row stride in elements (4160 B, breaks 4KB aliasing)

typedef __attribute__((ext_vector_type(8))) short short8;
typedef __attribute__((ext_vector_type(4))) float f32x4;

static __device__ inline unsigned pk_bf16(float a, float b) {
    __hip_bfloat162 h = __float22bfloat162_rn(make_float2(a, b));
    unsigned u; __builtin_memcpy(&u, &h, 4); return u;
}
static __device__ inline short f2bf_s(float a) {
    __hip_bfloat16 h = __float2bfloat16(a);
    short s; __builtin_memcpy(&s, &h, 2); return s;
}
static __device__ inline short8 neg8(short8 a) {
    short8 r;
    #pragma unroll
    for (int i = 0; i < 8; ++i) r[i] = a[i] ^ (short)0x8000;
    return r;
}

// async global->LDS, 16B per lane; LDS dest is WAVE-UNIFORM base (HW adds lane*16)
static __device__ inline void async16(const void* g, void* l) {
    __builtin_amdgcn_global_load_lds(
        (const __attribute__((address_space(1))) void*)g,
        (__attribute__((address_space(3))) void*)l,
        16, 0, 0);
}

// ---------------------------------------------------------------------------
// Kernel 0: build Bt[n][k] bf16. n = 64*g + h, g in [kr,ki,qr,qi,vr,vi];
// real: [Wr;-Wi], imag: [Wi;Wr].
// ---------------------------------------------------------------------------
__global__ __launch_bounds__(256) void prep_kernel(
    const float* __restrict__ Wkr, const float* __restrict__ Wki,
    const float* __restrict__ Wqr, const float* __restrict__ Wqi,
    const float* __restrict__ Wvr, const float* __restrict__ Wvi,
    short* __restrict__ Bt)
{
    const int n = blockIdx.x;
    const int g = n >> 6, h = n & 63;
    const int p = g >> 1;
    const bool im = g & 1;
    const float* Wr = (p == 0) ? Wkr : (p == 1) ? Wqr : Wvr;
    const float* Wi = (p == 0) ? Wki : (p == 1) ? Wqi : Wvi;
    const float* W1 = im ? Wi : Wr;
    const float* W2 = im ? Wr : Wi;
    const float s2 = im ? 1.f : -1.f;

    #pragma unroll
    for (int j = 0; j < 8; ++j) {
        int k = threadIdx.x + 256 * j;
        float v = (k < CC) ? W1[k * HH + h] : s2 * W2[(k - CC) * HH + h];
        Bt[(size_t)n * KK2 + k] = f2bf_s(v);
    }
}

// ---------------------------------------------------------------------------
// Kernel 1: bf16 MFMA GEMM, fp32 A staged DIRECTLY via global_load_lds
// (no convert pass, no reg-staging). BM=128 BN=64 BK=64, grid (128,6).
//  - A: fp32 tile [128][64] in LDS (32 KB), staged with 16B-granule XOR
//    swizzle applied to the per-lane GLOBAL source (m173); fragment read =
//    2x ds_read_b128 fp32 + 4x cvt_pk -> bf16 frag. Conflict-free (8 chunks
//    x 4 banks = 32 banks, 8 words/bank = exact BW floor).
//  - B: bf16 via async16, byte-identical to the proven R3 path.
//  - Wave layout 4x1 (wave w owns rows 32w..32w+31, ALL 64 cols): A read
//    from LDS exactly once (fp32 is 2x bytes; avoids the 2x wave-pair
//    redundancy of the 2x2 layout). MFMA/K-step/wave = 2mi x 4ni x 2kk = 16.
//  - Plain 2-barrier K-loop (R3-proven structure, no custom sync).
// All 6 comp-blocks of a row-panel land on one XCD (128%8==0) -> A fp32
// fetched from HBM ~once (128 MB), then L2 for the other 5 comps.
// ---------------------------------------------------------------------------
#define LDP 72    // epilogue G staging stride (elements)
#define STP 136   // epilogue sT row stride (elements), 16B-aligned

__global__ __launch_bounds__(256) void proj_gemm(
    const float* __restrict__ xr, const float* __restrict__ xi,
    const short* __restrict__ Bt,
    short* __restrict__ G, short* __restrict__ VT)
{
    __shared__ __attribute__((aligned(16))) float sAf[128 * 64];  // 32 KB fp32 A
    __shared__ __attribute__((aligned(16))) short sB[64 * 64];    // 8 KB bf16 B

    const int tid = threadIdx.x;
    const int mbase = blockIdx.x * 128;
    const int comp = blockIdx.y;                 // 0..5

    const int wave = tid >> 6, lane = tid & 63;
    const int quad = lane >> 4, lm = lane & 15;

    // B staging lane decomposition: 8 lanes x 16B cover one 128B row
    const int lgrp = lane >> 3;                  // row within 8-row group
    const int lslot = lane & 7;
    const int scolB = ((lslot ^ lgrp) << 4);     // swizzled byte col within row

    // A staging: per issue q (=wave*8+i), 1 KB = 4 fp32-rows of 256 B.
    // lane -> row 4q + (lane>>4), dest chunk slot lane&15; source chunk
    // is XOR-swizzled so the read side can un-swizzle conflict-free.
    const int arow_l = lane >> 4;                // 0..3
    const int acol_l = lane & 15;                // chunk slot 0..15

    const char* Bg = (const char*)(Bt + (size_t)comp * 64 * KK2);

    f32x4 acc[2][4] = {};

    for (int ks = 0; ks < KK2 / 64; ++ks) {
        const float* __restrict__ srcA = (ks < 16) ? xr : xi;
        const int kc = (ks & 15) * 64;

        // ---- A: 8 async16 per wave (32 KB tile) ----
        #pragma unroll
        for (int i = 0; i < 8; ++i) {
            int q = wave * 8 + i;
            int r = q * 4 + arow_l;
            int c = acol_l ^ (r & 7);            // swizzled source chunk
            async16((const char*)(srcA + (size_t)(mbase + r) * CC + kc) + (c << 4),
                    (char*)sAf + q * 1024);
        }
        // ---- B: 2 async16 per wave (8 KB tile) ----
        #pragma unroll
        for (int i = 0; i < 2; ++i) {
            int q = wave * 2 + i;
            async16(Bg + (size_t)(q * 8 + lgrp) * (KK2 * 2) + ks * 128 + scolB,
                    (char*)sB + q * 1024);
        }
        __syncthreads();   // drains vmcnt -> tile resident

        #pragma unroll
        for (int kk = 0; kk < 2; ++kk) {
            // A frags: rows 32*wave + 16*mi + lm, fp32 cols kk*32+quad*8..+7
            short8 af[2];
            #pragma unroll
            for (int mi = 0; mi < 2; ++mi) {
                const int row = 32 * wave + 16 * mi + lm;
                const int c0 = 8 * kk + 2 * quad;
                const int s = row & 7;
                f32x4 a0 = *(const f32x4*)&sAf[row * 64 + ((c0 ^ s) << 2)];
                f32x4 a1 = *(const f32x4*)&sAf[row * 64 + (((c0 + 1) ^ s) << 2)];
                uint4 u;
                u.x = pk_bf16(a0[0], a0[1]);
                u.y = pk_bf16(a0[2], a0[3]);
                u.z = pk_bf16(a1[0], a1[1]);
                u.w = pk_bf16(a1[2], a1[3]);
                __builtin_memcpy(&af[mi], &u, 16);
            }
            // B frags: rows 16*ni + lm (bf16), un-swizzled on read
            const int cs = (kk * 32 + quad * 8) ^ ((lm & 7) << 3);
            short8 bf[4];
            #pragma unroll
            for (int ni = 0; ni < 4; ++ni)
                bf[ni] = *(const short8*)&sB[(16 * ni + lm) * 64 + cs];

            #pragma unroll
            for (int mi = 0; mi < 2; ++mi)
                #pragma unroll
                for (int ni = 0; ni < 4; ++ni)
                    acc[mi][ni] = __builtin_amdgcn_mfma_f32_16x16x32_bf16(
                        af[mi], bf[ni], acc[mi][ni], 0, 0, 0);
        }
        __syncthreads();   // LDS reads done before next stage overwrites
    }

    // ---- epilogue: wave w owns output rows 32w..32w+31, cols 0..63 ----
    if (comp < 4) {
        short* sG = (short*)sAf;   // [128][LDP] = 18.4 KB <= 32 KB
        #pragma unroll
        for (int mi = 0; mi < 2; ++mi)
            #pragma unroll
            for (int ni = 0; ni < 4; ++ni)
                #pragma unroll
                for (int r = 0; r < 4; ++r)
                    sG[(32*wave + 16*mi + quad*4 + r) * LDP + 16*ni + lm] =
                        f2bf_s(acc[mi][ni][r]);
        __syncthreads();
        #pragma unroll
        for (int j = 0; j < 4; ++j) {
            int id = tid + 256 * j;
            int row = id >> 3, c8 = id & 7;       // 8 x 16B per row
            uint4 v = *(const uint4*)&sG[row * LDP + c8 * 8];
            *(uint4*)&G[(size_t)(mbase + row) * GN + comp*64 + c8*8] = v;
        }
    } else {
        short* sT = (short*)sAf;   // [64][STP] = 17.4 KB <= 32 KB
        const int vcomp = comp - 4;
        const int b = mbase >> 11;
        const int tb = mbase & 2047;
        #pragma unroll
        for (int mi = 0; mi < 2; ++mi)
            #pragma unroll
            for (int ni = 0; ni < 4; ++ni)
                #pragma unroll
                for (int r = 0; r < 4; ++r)
                    sT[(16*ni + lm) * STP + 32*wave + 16*mi + quad*4 + r] =
                        f2bf_s(acc[mi][ni][r]);
        __syncthreads();
        #pragma unroll
        for (int j = 0; j < 4; ++j) {
            int id = tid + 256 * j;
            int h = id >> 4, c = id & 15;         // 16 x 16B per h-row
            uint4 v = *(const uint4*)&sT[h * STP + c * 8];
            *(uint4*)&VT[(((size_t)vcomp*BB + b)*64 + h)*VTP + tb + c*8] = v;
        }
    }
}

// ---------------------------------------------------------------------------
// Kernel 2: MFMA flash attention, log2-domain online softmax.
// Grid is (b, j): linear bid % 8 == b -> all blocks of batch b on XCD b,
// K/V panels stay L2-resident (FETCH 6.2 MB measured, was 34.6).
// ---------------------------------------------------------------------------
#define PLDS 72
#define SC2 0.18033688f      // 0.125 * log2(e): softmax in exp2 domain

__global__ __launch_bounds__(256) void attn_kernel(
    const short* __restrict__ G,
    const short* __restrict__ VT,
    float* __restrict__ out)
{
    __shared__ float comb[4][16][128];
    __shared__ float cmw[4][16], clw[4][16];

    const int tid = threadIdx.x;
    const int wave = tid >> 6, lane = tid & 63;
    const int quad = lane >> 4, lm = lane & 15;
    const int b = blockIdx.x;                               // XCD affinity: bid%8 == b
    const int j = (int)(gridDim.y - 1) - (int)blockIdx.y;   // longest first
    const int qbase = j * 16;
    const int nkt = (j >> 2) + 1;    // k-tiles of 64 tokens

    const short* Qrow = G + ((size_t)(b*TT + qbase + lm)) * GN + 128;
    short8 A1[4], A2[4];
    #pragma unroll
    for (int ks = 0; ks < 4; ++ks)
        A1[ks] = *(const short8*)(Qrow + ks*32 + quad*8);
    A2[0] = A1[2]; A2[1] = A1[3];
    A2[2] = neg8(A1[0]); A2[3] = neg8(A1[1]);

    short8 ones;
    #pragma unroll
    for (int i = 0; i < 8; ++i) ones[i] = (short)0x3F80;   // bf16 1.0

    f32x4 Or[4], Oi[4];
    #pragma unroll
    for (int h = 0; h < 4; ++h)
        #pragma unroll
        for (int r = 0; r < 4; ++r) { Or[h][r] = 0.f; Oi[h][r] = 0.f; }
    f32x4 Ol = {0.f, 0.f, 0.f, 0.f};            // row-sums via ones-MFMA
    float m[4];
    #pragma unroll
    for (int r = 0; r < 4; ++r) m[r] = -INFINITY;

    short* Pw = (short*)&comb[wave][0][0];
    const short* Vrb = VT + (size_t)b * 64 * VTP;
    const short* Vib = VT + ((size_t)BB + b) * 64 * VTP;

    for (int kt = wave; kt < nkt; kt += 4) {
        const int kb = kt * 64;
        const short* Kt = G + ((size_t)(b*TT + kb)) * GN;

        // ---- hoist ALL K loads: one latency exposure instead of 4 ----
        short8 Kf[4][4];
        #pragma unroll
        for (int nt = 0; nt < 4; ++nt) {
            const short* Krow = Kt + (size_t)(nt*16 + lm) * GN;
            #pragma unroll
            for (int ks = 0; ks < 4; ++ks)
                Kf[nt][ks] = *(const short8*)(Krow + ks*32 + quad*8);
        }

        f32x4 mag[4];
        #pragma unroll
        for (int nt = 0; nt < 4; ++nt) {
            f32x4 sr = {0.f,0.f,0.f,0.f}, si = {0.f,0.f,0.f,0.f};
            __builtin_amdgcn_s_setprio(1);
            #pragma unroll
            for (int ks = 0; ks < 4; ++ks) {
                sr = __builtin_amdgcn_mfma_f32_16x16x32_bf16(A1[ks], Kf[nt][ks], sr, 0,0,0);
                si = __builtin_amdgcn_mfma_f32_16x16x32_bf16(A2[ks], Kf[nt][ks], si, 0,0,0);
            }
            __builtin_amdgcn_s_setprio(0);
            int tok = kb + nt*16 + lm;
            #pragma unroll
            for (int r = 0; r < 4; ++r) {
                float v = __builtin_amdgcn_sqrtf(
                              fmaf(sr[r], sr[r], fmaf(si[r], si[r], 1e-4f))) * SC2;
                int qrow = qbase + quad*4 + r;
                mag[nt][r] = (tok > qrow) ? -INFINITY : v;
            }
        }

        // ---- issue V loads now; softmax below hides their latency ----
        short8 Vr[4][2], Vi[4][2];
        #pragma unroll
        for (int ht = 0; ht < 4; ++ht) {
            const short* vr0 = Vrb + (size_t)(ht*16 + lm) * VTP + kb + quad*8;
            const short* vi0 = Vib + (size_t)(ht*16 + lm) * VTP + kb + quad*8;
            Vr[ht][0] = *(const short8*)(vr0);
            Vr[ht][1] = *(const short8*)(vr0 + 32);
            Vi[ht][0] = *(const short8*)(vi0);
            Vi[ht][1] = *(const short8*)(vi0 + 32);
        }

        float tm[4];
        #pragma unroll
        for (int r = 0; r < 4; ++r)
            tm[r] = fmaxf(fmaxf(mag[0][r], mag[1][r]), fmaxf(mag[2][r], mag[3][r]));
        #pragma unroll
        for (int d = 1; d < 16; d <<= 1)
            #pragma unroll
            for (int r = 0; r < 4; ++r)
                tm[r] = fmaxf(tm[r], __shfl_xor(tm[r], d, 16));

        // defer-max: rescale only when the running max actually grows past slack
        int need = (tm[0] > m[0] + 8.f) | (tm[1] > m[1] + 8.f) |
                   (tm[2] > m[2] + 8.f) | (tm[3] > m[3] + 8.f);
        if (__any(need)) {
            float al[4];
            #pragma unroll
            for (int r = 0; r < 4; ++r) {
                float mn = fmaxf(m[r], tm[r]);
                al[r] = __builtin_amdgcn_exp2f(m[r] - mn);
                m[r] = mn;
            }
            #pragma unroll
            for (int h = 0; h < 4; ++h)
                #pragma unroll
                for (int r = 0; r < 4; ++r) { Or[h][r] *= al[r]; Oi[h][r] *= al[r]; }
            #pragma unroll
            for (int r = 0; r < 4; ++r) Ol[r] *= al[r];
        }

        #pragma unroll
        for (int nt = 0; nt < 4; ++nt)
            #pragma unroll
            for (int r = 0; r < 4; ++r) {
                float p = __builtin_amdgcn_exp2f(mag[nt][r] - m[r]);
                Pw[(quad*4 + r) * PLDS + nt*16 + lm] = f2bf_s(p);
            }
        short8 Af0 = *(const short8*)&Pw[lm * PLDS + quad*8];
        short8 Af1 = *(const short8*)&Pw[lm * PLDS + 32 + quad*8];

        __builtin_amdgcn_s_setprio(1);
        Ol = __builtin_amdgcn_mfma_f32_16x16x32_bf16(Af0, ones, Ol, 0,0,0);
        Ol = __builtin_amdgcn_mfma_f32_16x16x32_bf16(Af1, ones, Ol, 0,0,0);
        __builtin_amdgcn_s_setprio(0);

        #pragma unroll
        for (int ht = 0; ht < 4; ++ht) {
            __builtin_amdgcn_s_setprio(1);
            Or[ht] = __builtin_amdgcn_mfma_f32_16x16x32_bf16(Af0, Vr[ht][0], Or[ht], 0,0,0);
            Or[ht] = __builtin_amdgcn_mfma_f32_16x16x32_bf16(Af1, Vr[ht][1], Or[ht], 0,0,0);
            Oi[ht] = __builtin_amdgcn_mfma_f32_16x16x32_bf16(Af0, Vi[ht][0], Oi[ht], 0,0,0);
            Oi[ht] = __builtin_amdgcn_mfma_f32_16x16x32_bf16(Af1, Vi[ht][1], Oi[ht], 0,0,0);
            __builtin_amdgcn_s_setprio(0);
        }
    }

    __syncthreads();

    #pragma unroll
    for (int ht = 0; ht < 4; ++ht)
        #pragma unroll
        for (int r = 0; r < 4; ++r) {
            comb[wave][quad*4 + r][ht*16 + lm]      = Or[ht][r];
            comb[wave][quad*4 + r][64 + ht*16 + lm] = Oi[ht][r];
        }
    if (lm == 0) {
        #pragma unroll
        for (int r = 0; r < 4; ++r) {
            cmw[wave][quad*4 + r] = m[r];
            clw[wave][quad*4 + r] = Ol[r];
        }
    }
    __syncthreads();

    for (int e = tid; e < 16*128; e += 256) {
        int q = e >> 7, h = e & 127;
        float mstar = fmaxf(fmaxf(cmw[0][q], cmw[1][q]), fmaxf(cmw[2][q], cmw[3][q]));
        float osum = 0.f, lsum = 0.f;
        #pragma unroll
        for (int w = 0; w < 4; ++w) {
            float f = __builtin_amdgcn_exp2f(cmw[w][q] - mstar);
            osum = fmaf(f, comb[w][q][h], osum);
            lsum = fmaf(f, clw[w][q], lsum);
        }
        float res = osum / lsum;
        int comp = h >> 6, hh = h & 63;
        out[(size_t)comp * NST + ((size_t)(b*TT + qbase + q)) * HH + hh] = res;
    }
}

extern "C" void kernel_launch(void* const* d_in, const int* in_sizes, int n_in,
                              void* d_out, int out_size, void* d_ws, size_t ws_size,
                              hipStream_t stream)
{
    const float* xr  = (const float*)d_in[0];
    const float* xi  = (const float*)d_in[1];
    const float* Wkr = (const float*)d_in[2];
    const float* Wki = (const float*)d_in[3];
    const float* Wqr = (const float*)d_in[4];
    const float* Wqi = (const float*)d_in[5];
    const float* Wvr = (const float*)d_in[6];
    const float* Wvi = (const float*)d_in[7];

    short* Bt = (short*)d_ws;                               // 1.5 MB
    short* G  = (short*)((char*)d_ws + (2u  << 20));        // 8 MB  [16384][256]
    short* VT = (short*)((char*)d_ws + (11u << 20));        // 4.3 MB [2][8][64][VTP]
    float* out = (float*)d_out;

    prep_kernel<<<NN, 256, 0, stream>>>(Wkr, Wki, Wqr, Wqi, Wvr, Wvi, Bt);

    dim3 g1(NROW / 128, 6);
    proj_gemm<<<g1, 256, 0, stream>>>(xr, xi, Bt, G, VT);

    dim3 g3(BB, TT / 16);   // bid%8 == b -> per-batch XCD affinity
    attn_kernel<<<g3, 256, 0, stream>>>(G, VT, out);
}